// Round 5
// baseline (237.882 us; speedup 1.0000x reference)
//
#include <hip/hip_runtime.h>

#define BB 2
#define NN 2048
#define EE 768
#define HH 12
#define DD 64
#define MM (BB*NN)      // 4096
#define E3 (3*EE)       // 2304
// 1/sqrt(768) * log2(e): scores in log2 domain -> P = exp2(s)
#define QSCALE 0.05205877280961602f

typedef __bf16 bf16x8 __attribute__((ext_vector_type(8)));
typedef float  f32x4  __attribute__((ext_vector_type(4)));
typedef float  f32x16 __attribute__((ext_vector_type(16)));
typedef unsigned short u16x8 __attribute__((ext_vector_type(8)));
typedef unsigned int   u32x4 __attribute__((ext_vector_type(4)));

#define MFMA(a,b,c)   __builtin_amdgcn_mfma_f32_16x16x32_bf16(a,b,c,0,0,0)
#define MFMA32(a,b,c) __builtin_amdgcn_mfma_f32_32x32x16_bf16(a,b,c,0,0,0)

__device__ __forceinline__ unsigned short f2bf(float f) {
    unsigned int u = __float_as_uint(f);
    u += 0x7FFFu + ((u >> 16) & 1u);     // round-to-nearest-even
    return (unsigned short)(u >> 16);
}

typedef __attribute__((address_space(3))) unsigned int as3u32;
typedef __attribute__((address_space(1))) unsigned int as1u32;
__device__ __forceinline__ void gll16(const void* g, void* l) {
    // lane i deposits its 16B at lds_base + i*16 (wave-uniform dest base)
    __builtin_amdgcn_global_load_lds((const as1u32*)(uintptr_t)g,
                                     (as3u32*)(unsigned int)(uintptr_t)l, 16, 0, 0);
}

// ---------------------------------------------------------------------------
// fused f32 -> bf16 cast of x, w_qkv, w_o (contiguous dsts in ws)
// ---------------------------------------------------------------------------
#define XB4 786432   // (MM*EE)/4
#define WQ4 442368   // (E3*EE)/4
#define WO4 147456   // (EE*EE)/4
__global__ __launch_bounds__(256)
void cast3(const float* __restrict__ x, const float* __restrict__ wq,
           const float* __restrict__ wo, unsigned short* __restrict__ dst) {
    int i = blockIdx.x * 256 + threadIdx.x;
    const float* src;
    int off;
    if (i < XB4)            { src = x;  off = i; }
    else if (i < XB4+WQ4)   { src = wq; off = i - XB4; }
    else                    { src = wo; off = i - XB4 - WQ4; }
    float4 v = ((const float4*)src)[off];
    ushort4 o;
    o.x = f2bf(v.x); o.y = f2bf(v.y); o.z = f2bf(v.z); o.w = f2bf(v.w);
    ((ushort4*)dst)[i] = o;
}

// ---------------------------------------------------------------------------
// bf16 MFMA NT GEMM (unchanged from round 4): C[m][c] = A[m][:]*W[c][:] + b[c]
// 128x128 tile, BK=32, 4 waves, wave 64x64 via 4x4 16x16x32 frags.
// ---------------------------------------------------------------------------
template<int MODE>
__global__ __launch_bounds__(256)
void gemm_bf16(const unsigned short* __restrict__ A, const unsigned short* __restrict__ W,
               const float* __restrict__ bias,
               unsigned short* __restrict__ o0, unsigned short* __restrict__ o1,
               unsigned short* __restrict__ o2, float* __restrict__ of, int Kd)
{
    __shared__ unsigned short As[128 * 32];
    __shared__ unsigned short Bs[128 * 32];

    const int tid = threadIdx.x;
    const int l = tid & 63;
    const int w = tid >> 6;
    const int m0 = blockIdx.x * 128;
    const int c0 = blockIdx.y * 128;
    const int wm = (w >> 1) * 64;
    const int wn = (w & 1) * 64;

    const int s0 = w * 2;
    const unsigned short* a_src0 = A + (size_t)(m0 + s0*16      + (l>>2)) * Kd + (l&3)*8;
    const unsigned short* a_src1 = A + (size_t)(m0 + (s0+1)*16  + (l>>2)) * Kd + (l&3)*8;
    const unsigned short* b_src0 = W + (size_t)(c0 + s0*16      + (l>>2)) * Kd + (l&3)*8;
    const unsigned short* b_src1 = W + (size_t)(c0 + (s0+1)*16  + (l>>2)) * Kd + (l&3)*8;
    unsigned short* a_dst0 = &As[s0*512];
    unsigned short* a_dst1 = &As[(s0+1)*512];
    unsigned short* b_dst0 = &Bs[s0*512];
    unsigned short* b_dst1 = &Bs[(s0+1)*512];

    const f32x4 zero4 = {0.f, 0.f, 0.f, 0.f};
    f32x4 acc[4][4];
    #pragma unroll
    for (int i = 0; i < 4; ++i)
        #pragma unroll
        for (int j = 0; j < 4; ++j) acc[i][j] = zero4;

    for (int k0 = 0; k0 < Kd; k0 += 32) {
        __syncthreads();
        gll16(a_src0 + k0, a_dst0);
        gll16(a_src1 + k0, a_dst1);
        gll16(b_src0 + k0, b_dst0);
        gll16(b_src1 + k0, b_dst1);
        __syncthreads();

        bf16x8 af[4], bf[4];
        #pragma unroll
        for (int i = 0; i < 4; ++i)
            af[i] = *(const bf16x8*)&As[(wm + 16*i + (l&15))*32 + (l>>4)*8];
        #pragma unroll
        for (int j = 0; j < 4; ++j)
            bf[j] = *(const bf16x8*)&Bs[(wn + 16*j + (l&15))*32 + (l>>4)*8];
        #pragma unroll
        for (int i = 0; i < 4; ++i)
            #pragma unroll
            for (int j = 0; j < 4; ++j)
                acc[i][j] = MFMA(af[i], bf[j], acc[i][j]);
    }

    if (MODE == 0) {
        #pragma unroll
        for (int j = 0; j < 4; ++j) {
            const int col = c0 + wn + 16*j + (l&15);
            const float bj = bias[col];
            #pragma unroll
            for (int i = 0; i < 4; ++i) {
                #pragma unroll
                for (int r = 0; r < 4; ++r) {
                    const int row = m0 + wm + 16*i + (l>>4)*4 + r;
                    of[(size_t)row * EE + col] = acc[i][j][r] + bj;
                }
            }
        }
    } else {
        const int sec = (c0 + wn) >> 6;        // = hh*3 + tt
        const int hh = sec / 3;
        const int tt = sec - hh*3;
        #pragma unroll
        for (int j = 0; j < 4; ++j) {
            const int col = c0 + wn + 16*j + (l&15);
            const int dcol = 16*j + (l&15);
            const float bj = bias[col];
            #pragma unroll
            for (int i = 0; i < 4; ++i) {
                const int row0 = m0 + wm + 16*i + (l>>4)*4;
                const int b = row0 >> 11;
                const int n = row0 & (NN - 1);
                if (tt == 2) {
                    ushort4 pk;
                    pk.x = f2bf(acc[i][j][0] + bj);
                    pk.y = f2bf(acc[i][j][1] + bj);
                    pk.z = f2bf(acc[i][j][2] + bj);
                    pk.w = f2bf(acc[i][j][3] + bj);
                    *(ushort4*)&o2[(((size_t)b*HH + hh)*DD + dcol)*NN + n] = pk;
                } else {
                    unsigned short* dst = (tt == 0) ? o0 : o1;
                    #pragma unroll
                    for (int r = 0; r < 4; ++r) {
                        float val = acc[i][j][r] + bj;
                        if (tt == 0) val *= QSCALE;
                        dst[(((size_t)b*HH + hh)*NN + n + r)*DD + dcol] = f2bf(val);
                    }
                }
            }
        }
    }
}

// ---------------------------------------------------------------------------
// MFMA flash attention, 32x32x16, S^T formulation.
// Block = 128 threads = 2 waves; wave wv owns 32 queries. Block = 64 queries
// of one (b,h). Grid 768 (1D): bh = id%24 (same-bh blocks share an XCD),
// qtile = id/24.
// S^T = K*Q^T: C col = q = lane&31 -> per-lane softmax, deferred denominator.
// P^T assembled IN REGISTERS for the PV B-operand via shfl_xor(32) pair
// exchange (C rows->B k-slices line up half-wave-symmetrically).
// K and V^T staged by global_load_lds(16B) into unpadded [row][64] tiles with
// XOR chunk swizzle (chunk ^= row&7) folded into per-lane SOURCE addresses.
// ---------------------------------------------------------------------------
__global__ __launch_bounds__(128)
void attn_mfma(const unsigned short* __restrict__ Q, const unsigned short* __restrict__ K,
               const unsigned short* __restrict__ Vt_g, unsigned short* __restrict__ ctx)
{
    __shared__ unsigned short Ks[64 * 64];   // [key][64], chunk-swizzled
    __shared__ unsigned short Vt[64 * 64];   // [d][64],  chunk-swizzled

    const int tid = threadIdx.x;
    const int l  = tid & 63;
    const int wv = tid >> 6;
    const int hf = l >> 5;        // half-wave
    const int lc = l & 31;
    const int l7 = l & 7;

    const int id = blockIdx.x;
    const int bh = id % 24;              // b*12 + h
    const int qt = id / 24;              // q-tile (64 q)
    const int b  = bh / 12;
    const int hh = bh - b*12;
    const size_t hbK = (size_t)bh * NN * DD;

    const f32x16 z16 = {0.f,0.f,0.f,0.f,0.f,0.f,0.f,0.f,
                        0.f,0.f,0.f,0.f,0.f,0.f,0.f,0.f};

    // Q B-frags (pre-scaled by QSCALE): B[n=q=lc][k=d=t*16+hf*8+j]
    const int qbase = qt*64 + wv*32;
    const unsigned short* qptr = Q + hbK + (size_t)(qbase + lc)*DD + hf*8;
    bf16x8 qf[4];
    #pragma unroll
    for (int t = 0; t < 4; ++t) qf[t] = *(const bf16x8*)(qptr + t*16);

    // staging source addresses (XOR swizzle in src, contiguous dest)
    const int lr3 = l >> 3;                    // row-in-group 0..7
    const int cx  = (l & 7) ^ (lr3 & 7);       // swizzled chunk
    const unsigned short* srcK0 = K   + hbK + (size_t)(32*wv + lr3)*DD + cx*8;
    const unsigned short* srcV0 = Vt_g + ((size_t)bh*DD + 32*wv + lr3)*NN + cx*8;

    f32x16 o0 = z16, o1 = z16;
    float lsum = 0.f;

    for (int kt = 0; kt < NN/64; ++kt) {
        __syncthreads();                       // prior-iter readers done
        const unsigned short* sk = srcK0 + (size_t)kt*64*DD;
        const unsigned short* sv = srcV0 + kt*64;
        #pragma unroll
        for (int oo = 0; oo < 4; ++oo) {
            gll16(sk + oo*8*DD, &Ks[(4*wv + oo)*512]);
            gll16(sv + (size_t)oo*8*NN, &Vt[(4*wv + oo)*512]);
        }
        __syncthreads();                       // writes visible (vmcnt drained)

        // S^T = K Q^T : A = K-frag [m=key][k], B = Q-frag. 2 key-blocks.
        f32x16 st0 = z16, st1 = z16;
        #pragma unroll
        for (int t = 0; t < 4; ++t) {
            const int ch = ((2*t + hf) ^ l7) * 8;
            bf16x8 kf0 = *(const bf16x8*)&Ks[(     lc)*64 + ch];
            bf16x8 kf1 = *(const bf16x8*)&Ks[(32 + lc)*64 + ch];
            st0 = MFMA32(kf0, qf[t], st0);
            st1 = MFMA32(kf1, qf[t], st1);
        }

        // P = exp2(S^T); pack pairs of consecutive keys (round-half-up + perm)
        unsigned int pk[2][8];
        #pragma unroll
        for (int m = 0; m < 8; ++m) {
            float e0 = __builtin_amdgcn_exp2f(st0[2*m]);
            float e1 = __builtin_amdgcn_exp2f(st0[2*m+1]);
            float e2 = __builtin_amdgcn_exp2f(st1[2*m]);
            float e3 = __builtin_amdgcn_exp2f(st1[2*m+1]);
            lsum += (e0 + e1) + (e2 + e3);
            pk[0][m] = __builtin_amdgcn_perm(__float_as_uint(e1) + 0x8000u,
                                             __float_as_uint(e0) + 0x8000u, 0x07060302u);
            pk[1][m] = __builtin_amdgcn_perm(__float_as_uint(e3) + 0x8000u,
                                             __float_as_uint(e2) + 0x8000u, 0x07060302u);
        }

        // O^T += V^T P^T. B-frag(P^T) assembled from pk via half-wave exchange.
        #pragma unroll
        for (int s = 0; s < 4; ++s) {
            const int kb = s >> 1;
            const int m0 = 4*(s & 1) + 2*hf;
            const unsigned int p0 = pk[kb][m0];
            const unsigned int p1 = pk[kb][m0 + 1];
            const unsigned int x0 = __shfl_xor(pk[kb][m0 ^ 2], 32);
            const unsigned int x1 = __shfl_xor(pk[kb][(m0 ^ 2) + 1], 32);
            u32x4 fr;
            fr[0] = hf ? x0 : p0;
            fr[1] = hf ? x1 : p1;
            fr[2] = hf ? p0 : x0;
            fr[3] = hf ? p1 : x1;
            bf16x8 pf = __builtin_bit_cast(bf16x8, fr);
            const int ch = ((2*s + hf) ^ l7) * 8;
            bf16x8 vf0 = *(const bf16x8*)&Vt[(     lc)*64 + ch];
            bf16x8 vf1 = *(const bf16x8*)&Vt[(32 + lc)*64 + ch];
            o0 = MFMA32(vf0, pf, o0);
            o1 = MFMA32(vf1, pf, o1);
        }
    }

    // denominator: lane q and lane q^32 each hold half the keys
    lsum += __shfl_xor(lsum, 32);
    const float inv = 1.f / lsum;

    // O^T C-layout: col=q=lc, row d = 32*db + 8*g + 4*hf + (r&3)
    const int qg = qbase + lc;
    unsigned short* cp = ctx + ((size_t)(b*NN + qg))*EE + hh*DD;
    #pragma unroll
    for (int g = 0; g < 4; ++g) {
        ushort4 pa, pb;
        pa.x = f2bf(o0[4*g+0]*inv); pa.y = f2bf(o0[4*g+1]*inv);
        pa.z = f2bf(o0[4*g+2]*inv); pa.w = f2bf(o0[4*g+3]*inv);
        pb.x = f2bf(o1[4*g+0]*inv); pb.y = f2bf(o1[4*g+1]*inv);
        pb.z = f2bf(o1[4*g+2]*inv); pb.w = f2bf(o1[4*g+3]*inv);
        *(ushort4*)(cp +      8*g + 4*hf) = pa;
        *(ushort4*)(cp + 32 + 8*g + 4*hf) = pb;
    }
}

// ---------------------------------------------------------------------------
extern "C" void kernel_launch(void* const* d_in, const int* in_sizes, int n_in,
                              void* d_out, int out_size, void* d_ws, size_t ws_size,
                              hipStream_t stream)
{
    const float* x     = (const float*)d_in[0];
    const float* w_qkv = (const float*)d_in[1];
    const float* b_qkv = (const float*)d_in[2];
    const float* w_o   = (const float*)d_in[3];
    const float* b_o   = (const float*)d_in[4];
    float* out = (float*)d_out;

    unsigned short* wsu = (unsigned short*)d_ws;
    const size_t XB = (size_t)MM * EE;
    const size_t WQ = (size_t)E3 * EE;
    const size_t WO = (size_t)EE * EE;
    const size_t HS = (size_t)BB * HH * NN * DD;
    unsigned short* xb   = wsu;
    unsigned short* wqb  = xb  + XB;
    unsigned short* wob  = wqb + WQ;
    unsigned short* qb   = wob + WO;
    unsigned short* kb   = qb  + HS;
    unsigned short* vtb  = kb  + HS;      // [B][H][D][N]
    unsigned short* ctxb = vtb + HS;

    cast3<<<(XB4 + WQ4 + WO4)/256, 256, 0, stream>>>(x, w_qkv, w_o, xb);

    dim3 g1(MM/128, E3/128);
    gemm_bf16<1><<<g1, 256, 0, stream>>>(xb, wqb, b_qkv, qb, kb, vtb, nullptr, EE);

    attn_mfma<<<768, 128, 0, stream>>>(qb, kb, vtb, ctxb);

    dim3 g3(MM/128, EE/128);
    gemm_bf16<0><<<g3, 256, 0, stream>>>(ctxb, wob, b_o, nullptr, nullptr, nullptr, out, EE);
}

// Round 6
// 204.505 us; speedup vs baseline: 1.1632x; 1.1632x over previous
//
#include <hip/hip_runtime.h>

#define BB 2
#define NN 2048
#define EE 768
#define HH 12
#define DD 64
#define MM (BB*NN)      // 4096
#define E3 (3*EE)       // 2304
// 1/sqrt(768) * log2(e): scores in log2 domain -> P = exp2(s)
#define QSCALE 0.05205877280961602f

typedef __bf16 bf16x8 __attribute__((ext_vector_type(8)));
typedef float  f32x4  __attribute__((ext_vector_type(4)));
typedef unsigned short u16x8 __attribute__((ext_vector_type(8)));

#define MFMA(a,b,c) __builtin_amdgcn_mfma_f32_16x16x32_bf16(a,b,c,0,0,0)

__device__ __forceinline__ unsigned short f2bf(float f) {
    unsigned int u = __float_as_uint(f);
    u += 0x7FFFu + ((u >> 16) & 1u);     // round-to-nearest-even
    return (unsigned short)(u >> 16);
}

typedef __attribute__((address_space(3))) unsigned int as3u32;
typedef __attribute__((address_space(1))) unsigned int as1u32;
__device__ __forceinline__ void gll16(const void* g, void* l) {
    // lane i deposits its 16B at lds_base + i*16 (wave-uniform dest base)
    __builtin_amdgcn_global_load_lds((const as1u32*)(uintptr_t)g,
                                     (as3u32*)(unsigned int)(uintptr_t)l, 16, 0, 0);
}

// ---------------------------------------------------------------------------
// fused f32 -> bf16 cast of x, w_qkv, w_o (contiguous dsts in ws)
// ---------------------------------------------------------------------------
#define XB4 786432   // (MM*EE)/4
#define WQ4 442368   // (E3*EE)/4
#define WO4 147456   // (EE*EE)/4
__global__ __launch_bounds__(256)
void cast3(const float* __restrict__ x, const float* __restrict__ wq,
           const float* __restrict__ wo, unsigned short* __restrict__ dst) {
    int i = blockIdx.x * 256 + threadIdx.x;
    const float* src;
    int off;
    if (i < XB4)            { src = x;  off = i; }
    else if (i < XB4+WQ4)   { src = wq; off = i - XB4; }
    else                    { src = wo; off = i - XB4 - WQ4; }
    float4 v = ((const float4*)src)[off];
    ushort4 o;
    o.x = f2bf(v.x); o.y = f2bf(v.y); o.z = f2bf(v.z); o.w = f2bf(v.w);
    ((ushort4*)dst)[i] = o;
}

// ---------------------------------------------------------------------------
// QKV GEMM: 256x128 tile, BK=32, 4 waves, wave tile 128x64 (8x4 frags).
// 32 MFMA : 12 ds_read_b128 : 6 gll16 per wave-iter.
// Scatter: q (scaled) [B][H][N][D], k [B][H][N][D], v transposed [B][H][D][N].
// ---------------------------------------------------------------------------
__global__ __launch_bounds__(256)
void gemm_qkv(const unsigned short* __restrict__ A, const unsigned short* __restrict__ W,
              const float* __restrict__ bias,
              unsigned short* __restrict__ o0, unsigned short* __restrict__ o1,
              unsigned short* __restrict__ o2)
{
    __shared__ unsigned short As[256 * 32];   // 16 KB
    __shared__ unsigned short Bs[128 * 32];   //  8 KB

    const int tid = threadIdx.x;
    const int l = tid & 63;
    const int w = tid >> 6;
    const int m0 = blockIdx.x * 256;
    const int c0 = blockIdx.y * 128;
    const int wm = (w >> 1) * 128;
    const int wn = (w & 1) * 64;

    // staging: wave w stages A rows [w*64, w*64+64) (4 chunks of 16 rows)
    // and B rows [w*32, w*32+32) (2 chunks). Within a chunk: row = l>>2,
    // kchunk = l&3 -> lane i writes dst + i*16 B (wave-uniform dest).
    const unsigned short* a_src[4];
    const unsigned short* b_src[2];
    unsigned short* a_dst[4];
    unsigned short* b_dst[2];
    #pragma unroll
    for (int s = 0; s < 4; ++s) {
        a_src[s] = A + (size_t)(m0 + w*64 + s*16 + (l>>2)) * EE + (l&3)*8;
        a_dst[s] = &As[(w*64 + s*16) * 32];
    }
    #pragma unroll
    for (int s = 0; s < 2; ++s) {
        b_src[s] = W + (size_t)(c0 + w*32 + s*16 + (l>>2)) * EE + (l&3)*8;
        b_dst[s] = &Bs[(w*32 + s*16) * 32];
    }

    const f32x4 zero4 = {0.f, 0.f, 0.f, 0.f};
    f32x4 acc[8][4];
    #pragma unroll
    for (int i = 0; i < 8; ++i)
        #pragma unroll
        for (int j = 0; j < 4; ++j) acc[i][j] = zero4;

    for (int k0 = 0; k0 < EE; k0 += 32) {
        __syncthreads();
        #pragma unroll
        for (int s = 0; s < 4; ++s) gll16(a_src[s] + k0, a_dst[s]);
        #pragma unroll
        for (int s = 0; s < 2; ++s) gll16(b_src[s] + k0, b_dst[s]);
        __syncthreads();

        bf16x8 af[8], bf[4];
        #pragma unroll
        for (int i = 0; i < 8; ++i)
            af[i] = *(const bf16x8*)&As[(wm + 16*i + (l&15))*32 + (l>>4)*8];
        #pragma unroll
        for (int j = 0; j < 4; ++j)
            bf[j] = *(const bf16x8*)&Bs[(wn + 16*j + (l&15))*32 + (l>>4)*8];
        #pragma unroll
        for (int i = 0; i < 8; ++i)
            #pragma unroll
            for (int j = 0; j < 4; ++j)
                acc[i][j] = MFMA(af[i], bf[j], acc[i][j]);
    }

    // epilogue: C/D col = l&15, row = (l>>4)*4 + r. wn section = one (h,t).
    const int sec = (c0 + wn) >> 6;        // = hh*3 + tt
    const int hh = sec / 3;
    const int tt = sec - hh*3;
    #pragma unroll
    for (int j = 0; j < 4; ++j) {
        const int col = c0 + wn + 16*j + (l&15);
        const int dcol = 16*j + (l&15);
        const float bj = bias[col];
        #pragma unroll
        for (int i = 0; i < 8; ++i) {
            const int row0 = m0 + wm + 16*i + (l>>4)*4;
            const int b = row0 >> 11;
            const int n = row0 & (NN - 1);
            if (tt == 2) {
                ushort4 pk;
                pk.x = f2bf(acc[i][j][0] + bj);
                pk.y = f2bf(acc[i][j][1] + bj);
                pk.z = f2bf(acc[i][j][2] + bj);
                pk.w = f2bf(acc[i][j][3] + bj);
                *(ushort4*)&o2[(((size_t)b*HH + hh)*DD + dcol)*NN + n] = pk;
            } else {
                unsigned short* dst = (tt == 0) ? o0 : o1;
                #pragma unroll
                for (int r = 0; r < 4; ++r) {
                    float val = acc[i][j][r] + bj;
                    if (tt == 0) val *= QSCALE;
                    dst[(((size_t)b*HH + hh)*NN + n + r)*DD + dcol] = f2bf(val);
                }
            }
        }
    }
}

// ---------------------------------------------------------------------------
// Output GEMM (round-4 structure): 128x128 tile, BK=32, fp32 store + bias.
// ---------------------------------------------------------------------------
__global__ __launch_bounds__(256)
void gemm_out(const unsigned short* __restrict__ A, const unsigned short* __restrict__ W,
              const float* __restrict__ bias, float* __restrict__ of)
{
    __shared__ unsigned short As[128 * 32];
    __shared__ unsigned short Bs[128 * 32];

    const int tid = threadIdx.x;
    const int l = tid & 63;
    const int w = tid >> 6;
    const int m0 = blockIdx.x * 128;
    const int c0 = blockIdx.y * 128;
    const int wm = (w >> 1) * 64;
    const int wn = (w & 1) * 64;

    const int s0 = w * 2;
    const unsigned short* a_src0 = A + (size_t)(m0 + s0*16      + (l>>2)) * EE + (l&3)*8;
    const unsigned short* a_src1 = A + (size_t)(m0 + (s0+1)*16  + (l>>2)) * EE + (l&3)*8;
    const unsigned short* b_src0 = W + (size_t)(c0 + s0*16      + (l>>2)) * EE + (l&3)*8;
    const unsigned short* b_src1 = W + (size_t)(c0 + (s0+1)*16  + (l>>2)) * EE + (l&3)*8;
    unsigned short* a_dst0 = &As[s0*512];
    unsigned short* a_dst1 = &As[(s0+1)*512];
    unsigned short* b_dst0 = &Bs[s0*512];
    unsigned short* b_dst1 = &Bs[(s0+1)*512];

    const f32x4 zero4 = {0.f, 0.f, 0.f, 0.f};
    f32x4 acc[4][4];
    #pragma unroll
    for (int i = 0; i < 4; ++i)
        #pragma unroll
        for (int j = 0; j < 4; ++j) acc[i][j] = zero4;

    for (int k0 = 0; k0 < EE; k0 += 32) {
        __syncthreads();
        gll16(a_src0 + k0, a_dst0);
        gll16(a_src1 + k0, a_dst1);
        gll16(b_src0 + k0, b_dst0);
        gll16(b_src1 + k0, b_dst1);
        __syncthreads();

        bf16x8 af[4], bf[4];
        #pragma unroll
        for (int i = 0; i < 4; ++i)
            af[i] = *(const bf16x8*)&As[(wm + 16*i + (l&15))*32 + (l>>4)*8];
        #pragma unroll
        for (int j = 0; j < 4; ++j)
            bf[j] = *(const bf16x8*)&Bs[(wn + 16*j + (l&15))*32 + (l>>4)*8];
        #pragma unroll
        for (int i = 0; i < 4; ++i)
            #pragma unroll
            for (int j = 0; j < 4; ++j)
                acc[i][j] = MFMA(af[i], bf[j], acc[i][j]);
    }

    #pragma unroll
    for (int j = 0; j < 4; ++j) {
        const int col = c0 + wn + 16*j + (l&15);
        const float bj = bias[col];
        #pragma unroll
        for (int i = 0; i < 4; ++i) {
            #pragma unroll
            for (int r = 0; r < 4; ++r) {
                const int row = m0 + wm + 16*i + (l>>4)*4 + r;
                of[(size_t)row * EE + col] = acc[i][j][r] + bj;
            }
        }
    }
}

// ---------------------------------------------------------------------------
// MFMA flash attention (round-4 16x16 structure, 1D XCD-grouped grid).
// Block = 64 Q-rows of one (b,h), 256 threads = 4 waves, wave w owns 16 q.
// Grid 768: bh = id%24 (24 = 0 mod 8 -> same-bh blocks share an XCD), qt = id/24.
// S^T = K*Q^T -> per-lane no-max softmax, deferred denominator.
// O^T = V^T*P^T; P^T packed b64 write / b128 read (per-wave LDS).
// ---------------------------------------------------------------------------
__global__ __launch_bounds__(256)
void attn_mfma(const unsigned short* __restrict__ Q, const unsigned short* __restrict__ K,
               const unsigned short* __restrict__ Vt_g, unsigned short* __restrict__ ctx)
{
    __shared__ unsigned short Ks[64 * 72];
    __shared__ unsigned short Vt[64 * 72];
    __shared__ unsigned short Pq[4 * 16 * 72];   // per-wave [q=16][key 64 +pad]

    const int tid = threadIdx.x;
    const int l = tid & 63;
    const int w = tid >> 6;
    const int quad = l >> 4;
    const int lc = l & 15;

    const int id = blockIdx.x;
    const int bh = id % 24;              // b*HH + h
    const int bq = id / 24;              // q-tile
    const int b  = bh / 12;
    const int h  = bh - b*12;
    const size_t hb = (size_t)bh * NN * DD;

    const f32x4 zero4 = {0.f, 0.f, 0.f, 0.f};

    // Q B-frags (pre-scaled by QSCALE): B[n=q=lc][k=d=quad*8+j]
    const int qrow = bq*64 + w*16 + lc;
    const bf16x8 qf0 = *(const bf16x8*)(Q + hb + (size_t)qrow*DD +      quad*8);
    const bf16x8 qf1 = *(const bf16x8*)(Q + hb + (size_t)qrow*DD + 32 + quad*8);

    f32x4 o[4];
    #pragma unroll
    for (int dj = 0; dj < 4; ++dj) o[dj] = zero4;
    float lsum = 0.f;

    // staging: 256 threads, row = tid>>2 (64 rows), chunk = tid&3 (16 elem)
    const int srow = tid >> 2;
    const int sc = tid & 3;
    const unsigned short* kbase = K + hb + (size_t)srow*DD + sc*16;
    const unsigned short* vbase = Vt_g + ((size_t)bh*DD + srow)*NN + sc*16;
    unsigned short* ksl = &Ks[srow*72 + sc*16];
    unsigned short* vsl = &Vt[srow*72 + sc*16];

    for (int kt = 0; kt < NN/64; ++kt) {
        const unsigned short* ksrc = kbase + (size_t)kt*64*DD;
        const unsigned short* vsrc = vbase + kt*64;
        u16x8 k0 = *(const u16x8*)ksrc;
        u16x8 k1 = *(const u16x8*)(ksrc + 8);
        u16x8 v0 = *(const u16x8*)vsrc;
        u16x8 v1 = *(const u16x8*)(vsrc + 8);
        __syncthreads();                 // prior-iter readers done
        *(u16x8*)ksl = k0;
        *(u16x8*)(ksl + 8) = k1;
        *(u16x8*)vsl = v0;
        *(u16x8*)(vsl + 8) = v1;
        __syncthreads();                 // writers done

        // S^T = K Q^T : A = K-frag, B = Q-frag. 4 key-frags x 2 k-steps.
        f32x4 st[4];
        #pragma unroll
        for (int jf = 0; jf < 4; ++jf) {
            bf16x8 kf0 = *(const bf16x8*)&Ks[(16*jf + lc)*72 +      quad*8];
            bf16x8 kf1 = *(const bf16x8*)&Ks[(16*jf + lc)*72 + 32 + quad*8];
            f32x4 acc0 = MFMA(kf0, qf0, zero4);
            st[jf] = MFMA(kf1, qf1, acc0);
        }

        // P = exp2(S^T). C layout: lane holds keys 16*jf + quad*4 + r, q = lc.
        #pragma unroll
        for (int jf = 0; jf < 4; ++jf) {
            float e0 = __builtin_amdgcn_exp2f(st[jf][0]);
            float e1 = __builtin_amdgcn_exp2f(st[jf][1]);
            float e2 = __builtin_amdgcn_exp2f(st[jf][2]);
            float e3 = __builtin_amdgcn_exp2f(st[jf][3]);
            lsum += (e0 + e1) + (e2 + e3);
            ushort4 pk;
            pk.x = f2bf(e0); pk.y = f2bf(e1); pk.z = f2bf(e2); pk.w = f2bf(e3);
            *(ushort4*)&Pq[w*1152 + lc*72 + 16*jf + quad*4] = pk;
        }

        // O^T += V^T P^T : A = V^T-frag, B = P^T-frag (b128, same wave)
        #pragma unroll
        for (int kb = 0; kb < 2; ++kb) {
            bf16x8 pf = *(const bf16x8*)&Pq[w*1152 + lc*72 + kb*32 + quad*8];
            #pragma unroll
            for (int dj = 0; dj < 4; ++dj) {
                bf16x8 vf = *(const bf16x8*)&Vt[(16*dj + lc)*72 + kb*32 + quad*8];
                o[dj] = MFMA(vf, pf, o[dj]);
            }
        }
    }

    // final denominator: reduce across the 4 quads (same q = lc)
    lsum += __shfl_xor(lsum, 16);
    lsum += __shfl_xor(lsum, 32);
    const float inv = 1.f / lsum;

    // O^T C-layout: row = d = 16*dj + quad*4 + r, col = q = lc -> packed store
    const int n = bq*64 + w*16 + lc;
    #pragma unroll
    for (int dj = 0; dj < 4; ++dj) {
        ushort4 pk;
        pk.x = f2bf(o[dj][0] * inv);
        pk.y = f2bf(o[dj][1] * inv);
        pk.z = f2bf(o[dj][2] * inv);
        pk.w = f2bf(o[dj][3] * inv);
        *(ushort4*)&ctx[((size_t)(b*NN + n))*EE + h*DD + 16*dj + quad*4] = pk;
    }
}

// ---------------------------------------------------------------------------
extern "C" void kernel_launch(void* const* d_in, const int* in_sizes, int n_in,
                              void* d_out, int out_size, void* d_ws, size_t ws_size,
                              hipStream_t stream)
{
    const float* x     = (const float*)d_in[0];
    const float* w_qkv = (const float*)d_in[1];
    const float* b_qkv = (const float*)d_in[2];
    const float* w_o   = (const float*)d_in[3];
    const float* b_o   = (const float*)d_in[4];
    float* out = (float*)d_out;

    unsigned short* wsu = (unsigned short*)d_ws;
    const size_t XB = (size_t)MM * EE;
    const size_t WQ = (size_t)E3 * EE;
    const size_t WO = (size_t)EE * EE;
    const size_t HS = (size_t)BB * HH * NN * DD;
    unsigned short* xb   = wsu;
    unsigned short* wqb  = xb  + XB;
    unsigned short* wob  = wqb + WQ;
    unsigned short* qb   = wob + WO;
    unsigned short* kb   = qb  + HS;
    unsigned short* vtb  = kb  + HS;      // [B][H][D][N]
    unsigned short* ctxb = vtb + HS;

    cast3<<<(XB4 + WQ4 + WO4)/256, 256, 0, stream>>>(x, w_qkv, w_o, xb);

    dim3 g1(MM/256, E3/128);   // 16 x 18
    gemm_qkv<<<g1, 256, 0, stream>>>(xb, wqb, b_qkv, qb, kb, vtb);

    attn_mfma<<<768, 256, 0, stream>>>(qb, kb, vtb, ctxb);

    dim3 g3(MM/128, EE/128);   // 32 x 6
    gemm_out<<<g3, 256, 0, stream>>>(ctxb, wob, b_o, out);
}

// Round 7
// 173.583 us; speedup vs baseline: 1.3704x; 1.1781x over previous
//
#include <hip/hip_runtime.h>

#define BB 2
#define NN 2048
#define EE 768
#define HH 12
#define DD 64
#define MM (BB*NN)      // 4096
#define E3 (3*EE)       // 2304
// 1/sqrt(768) * log2(e): scores in log2 domain -> P = exp2(s)
#define QSCALE 0.05205877280961602f

typedef __bf16 bf16x8 __attribute__((ext_vector_type(8)));
typedef float  f32x4  __attribute__((ext_vector_type(4)));
typedef unsigned short u16x8 __attribute__((ext_vector_type(8)));

#define MFMA(a,b,c) __builtin_amdgcn_mfma_f32_16x16x32_bf16(a,b,c,0,0,0)

__device__ __forceinline__ unsigned short f2bf(float f) {
    unsigned int u = __float_as_uint(f);
    u += 0x7FFFu + ((u >> 16) & 1u);     // round-to-nearest-even
    return (unsigned short)(u >> 16);
}

typedef __attribute__((address_space(3))) unsigned int as3u32;
typedef __attribute__((address_space(1))) unsigned int as1u32;
__device__ __forceinline__ void gll16(const void* g, void* l) {
    // lane i deposits its 16B at lds_base + i*16 (wave-uniform dest base)
    __builtin_amdgcn_global_load_lds((const as1u32*)(uintptr_t)g,
                                     (as3u32*)(unsigned int)(uintptr_t)l, 16, 0, 0);
}

// ---------------------------------------------------------------------------
// fused f32 -> bf16 cast of x, w_qkv, w_o (contiguous dsts in ws)
// ---------------------------------------------------------------------------
#define XB4 786432   // (MM*EE)/4
#define WQ4 442368   // (E3*EE)/4
#define WO4 147456   // (EE*EE)/4
__global__ __launch_bounds__(256)
void cast3(const float* __restrict__ x, const float* __restrict__ wq,
           const float* __restrict__ wo, unsigned short* __restrict__ dst) {
    int i = blockIdx.x * 256 + threadIdx.x;
    const float* src;
    int off;
    if (i < XB4)            { src = x;  off = i; }
    else if (i < XB4+WQ4)   { src = wq; off = i - XB4; }
    else                    { src = wo; off = i - XB4 - WQ4; }
    float4 v = ((const float4*)src)[off];
    ushort4 o;
    o.x = f2bf(v.x); o.y = f2bf(v.y); o.z = f2bf(v.z); o.w = f2bf(v.w);
    ((ushort4*)dst)[i] = o;
}

// ---------------------------------------------------------------------------
// QKV GEMM (round-4 known-good): 128x128 tile, BK=32, 4 waves, wave 64x64.
// Scatter: q (scaled) [B][H][N][D], k [B][H][N][D], v transposed [B][H][D][N].
// ---------------------------------------------------------------------------
__global__ __launch_bounds__(256)
void gemm_qkv(const unsigned short* __restrict__ A, const unsigned short* __restrict__ W,
              const float* __restrict__ bias,
              unsigned short* __restrict__ o0, unsigned short* __restrict__ o1,
              unsigned short* __restrict__ o2)
{
    __shared__ unsigned short As[128 * 32];
    __shared__ unsigned short Bs[128 * 32];

    const int tid = threadIdx.x;
    const int l = tid & 63;
    const int w = tid >> 6;
    const int m0 = blockIdx.x * 128;
    const int c0 = blockIdx.y * 128;
    const int wm = (w >> 1) * 64;
    const int wn = (w & 1) * 64;

    const int s0 = w * 2;
    const unsigned short* a_src0 = A + (size_t)(m0 + s0*16      + (l>>2)) * EE + (l&3)*8;
    const unsigned short* a_src1 = A + (size_t)(m0 + (s0+1)*16  + (l>>2)) * EE + (l&3)*8;
    const unsigned short* b_src0 = W + (size_t)(c0 + s0*16      + (l>>2)) * EE + (l&3)*8;
    const unsigned short* b_src1 = W + (size_t)(c0 + (s0+1)*16  + (l>>2)) * EE + (l&3)*8;
    unsigned short* a_dst0 = &As[s0*512];
    unsigned short* a_dst1 = &As[(s0+1)*512];
    unsigned short* b_dst0 = &Bs[s0*512];
    unsigned short* b_dst1 = &Bs[(s0+1)*512];

    const f32x4 zero4 = {0.f, 0.f, 0.f, 0.f};
    f32x4 acc[4][4];
    #pragma unroll
    for (int i = 0; i < 4; ++i)
        #pragma unroll
        for (int j = 0; j < 4; ++j) acc[i][j] = zero4;

    for (int k0 = 0; k0 < EE; k0 += 32) {
        __syncthreads();
        gll16(a_src0 + k0, a_dst0);
        gll16(a_src1 + k0, a_dst1);
        gll16(b_src0 + k0, b_dst0);
        gll16(b_src1 + k0, b_dst1);
        __syncthreads();

        bf16x8 af[4], bf[4];
        #pragma unroll
        for (int i = 0; i < 4; ++i)
            af[i] = *(const bf16x8*)&As[(wm + 16*i + (l&15))*32 + (l>>4)*8];
        #pragma unroll
        for (int j = 0; j < 4; ++j)
            bf[j] = *(const bf16x8*)&Bs[(wn + 16*j + (l&15))*32 + (l>>4)*8];
        #pragma unroll
        for (int i = 0; i < 4; ++i)
            #pragma unroll
            for (int j = 0; j < 4; ++j)
                acc[i][j] = MFMA(af[i], bf[j], acc[i][j]);
    }

    // epilogue: C/D col = l&15, row = (l>>4)*4 + r. wn section = one (h,t).
    const int sec = (c0 + wn) >> 6;        // = hh*3 + tt
    const int hh = sec / 3;
    const int tt = sec - hh*3;
    #pragma unroll
    for (int j = 0; j < 4; ++j) {
        const int col = c0 + wn + 16*j + (l&15);
        const int dcol = 16*j + (l&15);
        const float bj = bias[col];
        #pragma unroll
        for (int i = 0; i < 4; ++i) {
            const int row0 = m0 + wm + 16*i + (l>>4)*4;
            const int b = row0 >> 11;
            const int n = row0 & (NN - 1);
            if (tt == 2) {
                ushort4 pk;
                pk.x = f2bf(acc[i][j][0] + bj);
                pk.y = f2bf(acc[i][j][1] + bj);
                pk.z = f2bf(acc[i][j][2] + bj);
                pk.w = f2bf(acc[i][j][3] + bj);
                *(ushort4*)&o2[(((size_t)b*HH + hh)*DD + dcol)*NN + n] = pk;
            } else {
                unsigned short* dst = (tt == 0) ? o0 : o1;
                #pragma unroll
                for (int r = 0; r < 4; ++r) {
                    float val = acc[i][j][r] + bj;
                    if (tt == 0) val *= QSCALE;
                    dst[(((size_t)b*HH + hh)*NN + n + r)*DD + dcol] = f2bf(val);
                }
            }
        }
    }
}

// ---------------------------------------------------------------------------
// Output GEMM: 64x128 tile, BK=32, 4 waves, wave tile 32x64 (2x4 frags).
// Grid (64,6) = 384 blocks (was 192 at 128x128 -> latency-bound).
// ---------------------------------------------------------------------------
__global__ __launch_bounds__(256)
void gemm_out(const unsigned short* __restrict__ A, const unsigned short* __restrict__ W,
              const float* __restrict__ bias, float* __restrict__ of)
{
    __shared__ unsigned short As[64 * 32];    // 4 KB
    __shared__ unsigned short Bs[128 * 32];   // 8 KB

    const int tid = threadIdx.x;
    const int l = tid & 63;
    const int w = tid >> 6;
    const int m0 = blockIdx.x * 64;
    const int c0 = blockIdx.y * 128;
    const int wm = (w >> 1) * 32;
    const int wn = (w & 1) * 64;

    // staging: 12 chunks of 16 rows (4 A + 8 B), wave w stages 3w..3w+2
    const unsigned short* s_src[3];
    unsigned short* s_dst[3];
    #pragma unroll
    for (int s = 0; s < 3; ++s) {
        const int ch = 3*w + s;
        if (ch < 4) {
            s_src[s] = A + (size_t)(m0 + ch*16 + (l>>2)) * EE + (l&3)*8;
            s_dst[s] = &As[ch*512];
        } else {
            s_src[s] = W + (size_t)(c0 + (ch-4)*16 + (l>>2)) * EE + (l&3)*8;
            s_dst[s] = &Bs[(ch-4)*512];
        }
    }

    const f32x4 zero4 = {0.f, 0.f, 0.f, 0.f};
    f32x4 acc[2][4];
    #pragma unroll
    for (int i = 0; i < 2; ++i)
        #pragma unroll
        for (int j = 0; j < 4; ++j) acc[i][j] = zero4;

    for (int k0 = 0; k0 < EE; k0 += 32) {
        __syncthreads();
        #pragma unroll
        for (int s = 0; s < 3; ++s) gll16(s_src[s] + k0, s_dst[s]);
        __syncthreads();

        bf16x8 af[2], bf[4];
        #pragma unroll
        for (int i = 0; i < 2; ++i)
            af[i] = *(const bf16x8*)&As[(wm + 16*i + (l&15))*32 + (l>>4)*8];
        #pragma unroll
        for (int j = 0; j < 4; ++j)
            bf[j] = *(const bf16x8*)&Bs[(wn + 16*j + (l&15))*32 + (l>>4)*8];
        #pragma unroll
        for (int i = 0; i < 2; ++i)
            #pragma unroll
            for (int j = 0; j < 4; ++j)
                acc[i][j] = MFMA(af[i], bf[j], acc[i][j]);
    }

    #pragma unroll
    for (int j = 0; j < 4; ++j) {
        const int col = c0 + wn + 16*j + (l&15);
        const float bj = bias[col];
        #pragma unroll
        for (int i = 0; i < 2; ++i) {
            #pragma unroll
            for (int r = 0; r < 4; ++r) {
                const int row = m0 + wm + 16*i + (l>>4)*4 + r;
                of[(size_t)row * EE + col] = acc[i][j][r] + bj;
            }
        }
    }
}

// ---------------------------------------------------------------------------
// MFMA flash attention (r4 structure, XOR-swizzled unpadded LDS).
// Block = 64 Q-rows of one (b,h), 256 threads = 4 waves, wave w owns 16 q.
// Grid 768: bh = id%24 (same-bh blocks share an XCD), qt = id/24.
// S^T = K*Q^T -> per-lane no-max softmax, deferred denominator.
// Ks/Vt: [row][64], 16B-chunk phys = chunk ^ (row&7)  (<=2-way everywhere).
// Pq: per-wave [q][64], 8B-chunk phys = chunk ^ (q&14) (b64 write / b128 read).
// ---------------------------------------------------------------------------
__global__ __launch_bounds__(256)
void attn_mfma(const unsigned short* __restrict__ Q, const unsigned short* __restrict__ K,
               const unsigned short* __restrict__ Vt_g, unsigned short* __restrict__ ctx)
{
    __shared__ unsigned short Ks[64 * 64];       // 8 KB
    __shared__ unsigned short Vt[64 * 64];       // 8 KB
    __shared__ unsigned short Pq[4 * 16 * 64];   // 8 KB, per-wave [q=16][64]

    const int tid = threadIdx.x;
    const int l = tid & 63;
    const int w = tid >> 6;
    const int quad = l >> 4;
    const int lc = l & 15;
    const int x7 = lc & 7;

    const int id = blockIdx.x;
    const int bh = id % 24;              // b*HH + h
    const int bq = id / 24;              // q-tile
    const int b  = bh / 12;
    const int h  = bh - b*12;
    const size_t hb = (size_t)bh * NN * DD;

    const f32x4 zero4 = {0.f, 0.f, 0.f, 0.f};

    // Q B-frags (pre-scaled by QSCALE): B[n=q=lc][k=d=quad*8+j]
    const int qrow = bq*64 + w*16 + lc;
    const bf16x8 qf0 = *(const bf16x8*)(Q + hb + (size_t)qrow*DD +      quad*8);
    const bf16x8 qf1 = *(const bf16x8*)(Q + hb + (size_t)qrow*DD + 32 + quad*8);

    f32x4 o[4];
    #pragma unroll
    for (int dj = 0; dj < 4; ++dj) o[dj] = zero4;
    float lsum = 0.f;

    // staging: 256 threads, row = tid>>2 (64 rows), sc = tid&3 (16 elem = 2 chunks)
    const int srow = tid >> 2;
    const int sc = tid & 3;
    const unsigned short* kbase = K + hb + (size_t)srow*DD + sc*16;
    const unsigned short* vbase = Vt_g + ((size_t)bh*DD + srow)*NN + sc*16;
    const int c0s = ((2*sc)     ^ (srow & 7)) * 8;
    const int c1s = ((2*sc + 1) ^ (srow & 7)) * 8;
    unsigned short* ksl0 = &Ks[srow*64 + c0s];
    unsigned short* ksl1 = &Ks[srow*64 + c1s];
    unsigned short* vsl0 = &Vt[srow*64 + c0s];
    unsigned short* vsl1 = &Vt[srow*64 + c1s];

    // frag-read swizzled chunk offsets (QK kb0/kb1 == PV kb0/kb1)
    const int chq0 = ((    quad) ^ x7) * 8;
    const int chq1 = ((4 + quad) ^ x7) * 8;
    // Pq offsets
    const int pw = w * 1024;
    const int prd0 = pw + lc*64 + (((      2*quad) ^ (lc & 14)) * 4);
    const int prd1 = pw + lc*64 + (((8 +   2*quad) ^ (lc & 14)) * 4);

    for (int kt = 0; kt < NN/64; ++kt) {
        const unsigned short* ksrc = kbase + (size_t)kt*64*DD;
        const unsigned short* vsrc = vbase + kt*64;
        u16x8 k0 = *(const u16x8*)ksrc;
        u16x8 k1 = *(const u16x8*)(ksrc + 8);
        u16x8 v0 = *(const u16x8*)vsrc;
        u16x8 v1 = *(const u16x8*)(vsrc + 8);
        __syncthreads();                 // prior-iter readers done
        *(u16x8*)ksl0 = k0;
        *(u16x8*)ksl1 = k1;
        *(u16x8*)vsl0 = v0;
        *(u16x8*)vsl1 = v1;
        __syncthreads();                 // writers done

        // S^T = K Q^T : A = K-frag, B = Q-frag. 4 key-frags x 2 k-steps.
        f32x4 st[4];
        #pragma unroll
        for (int jf = 0; jf < 4; ++jf) {
            bf16x8 kf0 = *(const bf16x8*)&Ks[(16*jf + lc)*64 + chq0];
            bf16x8 kf1 = *(const bf16x8*)&Ks[(16*jf + lc)*64 + chq1];
            f32x4 acc0 = MFMA(kf0, qf0, zero4);
            st[jf] = MFMA(kf1, qf1, acc0);
        }

        // P = exp2(S^T). C layout: lane holds keys 16*jf + quad*4 + r, q = lc.
        #pragma unroll
        for (int jf = 0; jf < 4; ++jf) {
            float e0 = __builtin_amdgcn_exp2f(st[jf][0]);
            float e1 = __builtin_amdgcn_exp2f(st[jf][1]);
            float e2 = __builtin_amdgcn_exp2f(st[jf][2]);
            float e3 = __builtin_amdgcn_exp2f(st[jf][3]);
            lsum += (e0 + e1) + (e2 + e3);
            ushort4 pk;
            pk.x = f2bf(e0); pk.y = f2bf(e1); pk.z = f2bf(e2); pk.w = f2bf(e3);
            *(ushort4*)&Pq[pw + lc*64 + (((4*jf + quad) ^ (lc & 14)) * 4)] = pk;
        }

        // O^T += V^T P^T : A = V^T-frag, B = P^T-frag (b128, same wave)
        {
            bf16x8 pf0 = *(const bf16x8*)&Pq[prd0];
            bf16x8 pf1 = *(const bf16x8*)&Pq[prd1];
            #pragma unroll
            for (int dj = 0; dj < 4; ++dj) {
                bf16x8 vf0 = *(const bf16x8*)&Vt[(16*dj + lc)*64 + chq0];
                bf16x8 vf1 = *(const bf16x8*)&Vt[(16*dj + lc)*64 + chq1];
                o[dj] = MFMA(vf0, pf0, o[dj]);
                o[dj] = MFMA(vf1, pf1, o[dj]);
            }
        }
    }

    // final denominator: reduce across the 4 quads (same q = lc)
    lsum += __shfl_xor(lsum, 16);
    lsum += __shfl_xor(lsum, 32);
    const float inv = 1.f / lsum;

    // O^T C-layout: row = d = 16*dj + quad*4 + r, col = q = lc -> packed store
    const int n = bq*64 + w*16 + lc;
    #pragma unroll
    for (int dj = 0; dj < 4; ++dj) {
        ushort4 pk;
        pk.x = f2bf(o[dj][0] * inv);
        pk.y = f2bf(o[dj][1] * inv);
        pk.z = f2bf(o[dj][2] * inv);
        pk.w = f2bf(o[dj][3] * inv);
        *(ushort4*)&ctx[((size_t)(b*NN + n))*EE + h*DD + 16*dj + quad*4] = pk;
    }
}

// ---------------------------------------------------------------------------
extern "C" void kernel_launch(void* const* d_in, const int* in_sizes, int n_in,
                              void* d_out, int out_size, void* d_ws, size_t ws_size,
                              hipStream_t stream)
{
    const float* x     = (const float*)d_in[0];
    const float* w_qkv = (const float*)d_in[1];
    const float* b_qkv = (const float*)d_in[2];
    const float* w_o   = (const float*)d_in[3];
    const float* b_o   = (const float*)d_in[4];
    float* out = (float*)d_out;

    unsigned short* wsu = (unsigned short*)d_ws;
    const size_t XB = (size_t)MM * EE;
    const size_t WQ = (size_t)E3 * EE;
    const size_t WO = (size_t)EE * EE;
    const size_t HS = (size_t)BB * HH * NN * DD;
    unsigned short* xb   = wsu;
    unsigned short* wqb  = xb  + XB;
    unsigned short* wob  = wqb + WQ;
    unsigned short* qb   = wob + WO;
    unsigned short* kb   = qb  + HS;
    unsigned short* vtb  = kb  + HS;      // [B][H][D][N]
    unsigned short* ctxb = vtb + HS;

    cast3<<<(XB4 + WQ4 + WO4)/256, 256, 0, stream>>>(x, w_qkv, w_o, xb);

    dim3 g1(MM/128, E3/128);   // 32 x 18 = 576 blocks
    gemm_qkv<<<g1, 256, 0, stream>>>(xb, wqb, b_qkv, qb, kb, vtb);

    attn_mfma<<<768, 256, 0, stream>>>(qb, kb, vtb, ctxb);

    dim3 g3(MM/64, EE/128);    // 64 x 6 = 384 blocks
    gemm_out<<<g3, 256, 0, stream>>>(ctxb, wob, b_o, out);
}